// Round 15
// baseline (279.764 us; speedup 1.0000x reference)
//
#include <hip/hip_runtime.h>
#include <hip/hip_bf16.h>
#include <hip/hip_fp16.h>

#define NN 50000
#define EE 800000
#define SCAN_B 196   // ceil(NN/256)
#define EB 3125      // ceil(EE/256)

typedef unsigned int uint;
typedef unsigned short ushort;
typedef __attribute__((ext_vector_type(8))) short s16x8;
typedef __attribute__((ext_vector_type(4))) float f32x4;
typedef __attribute__((ext_vector_type(2))) _Float16 h16x2;

__device__ __forceinline__ float lrelu(float x, float s){ return fmaxf(x, x * s); }

__device__ __forceinline__ ushort bf16_rne(float x){
  uint u = __float_as_uint(x);
  return (ushort)((u + 0x7FFFu + ((u >> 16) & 1u)) >> 16);
}
__device__ __forceinline__ float bf16f(ushort h){ return __uint_as_float(((uint)h) << 16); }

__device__ __forceinline__ float dpp_add4(float x){
  int v = __float_as_int(x), t;
  t = __builtin_amdgcn_update_dpp(0, v, 0xB1, 0xF, 0xF, true);
  v = __float_as_int(__int_as_float(v) + __int_as_float(t));
  t = __builtin_amdgcn_update_dpp(0, v, 0x4E, 0xF, 0xF, true);
  v = __float_as_int(__int_as_float(v) + __int_as_float(t));
  return __int_as_float(v);
}

__device__ __forceinline__ float dpp_add16(float x){
  int v = __float_as_int(x), t;
  t = __builtin_amdgcn_update_dpp(0, v, 0xB1, 0xF, 0xF, true);
  v = __float_as_int(__int_as_float(v) + __int_as_float(t));
  t = __builtin_amdgcn_update_dpp(0, v, 0x4E, 0xF, 0xF, true);
  v = __float_as_int(__int_as_float(v) + __int_as_float(t));
  t = __builtin_amdgcn_update_dpp(0, v, 0x141, 0xF, 0xF, true);
  v = __float_as_int(__int_as_float(v) + __int_as_float(t));
  t = __builtin_amdgcn_update_dpp(0, v, 0x140, 0xF, 0xF, true);
  v = __float_as_int(__int_as_float(v) + __int_as_float(t));
  return __int_as_float(v);
}

// ---------------- launch A: prep_w + zero(deg) + detect ----------------
__global__ void prep_misc_kernel(const float* __restrict__ w0, const float* __restrict__ w1,
                                 const float* __restrict__ w2, const float* __restrict__ w3,
                                 const float* __restrict__ w4, const float* __restrict__ w5,
                                 ushort* __restrict__ wt,
                                 const int* __restrict__ ei, int* __restrict__ flag,
                                 int* __restrict__ deg){
  const int b = blockIdx.x;
  if (b < 320){
    int gid = b * 256 + threadIdx.x;
    if (gid >= 81920) return;
    const int KK[6]    = {64, 128, 128, 128, 128, 128};
    const int CC[6]    = {128, 128, 128, 128, 128, 64};
    const int cumel[7] = {0, 8192, 24576, 40960, 57344, 73728, 81920};
    int j = 0;
    while (gid >= cumel[j + 1]) j++;
    int local = gid - cumel[j];
    int K = KK[j], C = CC[j];
    int k = local / C, c = local % C;
    const float* src = (j == 0) ? w0 : (j == 1) ? w1 : (j == 2) ? w2 : (j == 3) ? w3 : (j == 4) ? w4 : w5;
    wt[cumel[j] + c * K + k] = bf16_rne(src[local]);
  } else if (b < 320 + SCAN_B){
    int i = (b - 320) * 256 + threadIdx.x;
    if (i < NN) deg[i] = 0;
  } else {
    __shared__ int any;
    if (threadIdx.x == 0) any = 0;
    __syncthreads();
    if (ei[2 * threadIdx.x + 1] != 0) atomicOr(&any, 1);
    __syncthreads();
    if (threadIdx.x == 0) *flag = (any == 0) ? 1 : 0;
  }
}

// ---------------- scans ----------------
__global__ void scan1_kernel(const int* __restrict__ deg, int* __restrict__ rowptr,
                             int* __restrict__ bsum){
  __shared__ int tmp[256];
  int tid = threadIdx.x;
  int idx = blockIdx.x * 256 + tid;
  int v = (idx < NN) ? deg[idx] : 0;
  tmp[tid] = v;
  __syncthreads();
  for (int off = 1; off < 256; off <<= 1){
    int t = (tid >= off) ? tmp[tid - off] : 0;
    __syncthreads();
    tmp[tid] += t;
    __syncthreads();
  }
  if (idx < NN) rowptr[idx] = tmp[tid] - v;
  if (tid == 255) bsum[blockIdx.x] = tmp[255];
}

__global__ void scan2_kernel(const int* __restrict__ bsum, int* __restrict__ boff,
                             int* __restrict__ rowptr){
  __shared__ int tmp[256];
  int tid = threadIdx.x;
  int v = (tid < SCAN_B) ? bsum[tid] : 0;
  tmp[tid] = v;
  __syncthreads();
  for (int off = 1; off < 256; off <<= 1){
    int t = (tid >= off) ? tmp[tid - off] : 0;
    __syncthreads();
    tmp[tid] += t;
    __syncthreads();
  }
  if (tid < SCAN_B) boff[tid] = tmp[tid] - v;
  if (tid == 255) rowptr[NN] = tmp[255];
}

__global__ void scan3_kernel(int* __restrict__ rowptr, const int* __restrict__ boff,
                             int* __restrict__ deg){
  int i = blockIdx.x * 256 + threadIdx.x;
  if (i < NN){ rowptr[i] += boff[blockIdx.x]; deg[i] = 0; }   // deg -> cursor
}

// ---------------- tail bodies ----------------
__device__ __forceinline__ void count_body(int e, const int* __restrict__ ei,
                                           const int* __restrict__ flag, int* __restrict__ deg){
  if (e >= EE) return;
  int d;
  if (*flag){
    const long long* eil = (const long long*)ei;
    d = (int)eil[EE + e];
  } else {
    d = ei[EE + e];
  }
  atomicAdd(&deg[d], 1);
}

__device__ __forceinline__ void scatter_body(int e, const int* __restrict__ ei,
                                             const int* __restrict__ flag,
                                             const int* __restrict__ rowptr,
                                             int* __restrict__ cursor, int* __restrict__ csr){
  if (e >= EE) return;
  int s, d;
  if (*flag){
    const long long* eil = (const long long*)ei;
    s = (int)eil[e];
    d = (int)eil[EE + e];
  } else {
    s = ei[e];
    d = ei[EE + e];
  }
  int pos = atomicAdd(&cursor[d], 1);
  csr[rowptr[d] + pos] = s;
}

// ---------------- MFMA GEMM body (W staged ONE PHASE AT A TIME -> 32KB LDS) ----------------
template<int KIN, int NOUT, int EPI, bool DUAL, bool FUSE>
__device__ __forceinline__ void gemm_body(int bid,
                                 const float* __restrict__ A,
                                 const ushort* __restrict__ Wt, const float* __restrict__ bias,
                                 const ushort* __restrict__ Wt2, const float* __restrict__ bias2,
                                 const float* __restrict__ bn_g, const float* __restrict__ bn_b,
                                 const float* __restrict__ bn_m, const float* __restrict__ bn_v,
                                 ushort* __restrict__ OUTH, float* __restrict__ OUTF, int n){
  constexpr int KF = KIN / 32;
  constexpr int NF = NOUT / 16;
  constexpr int WELEM = KIN * NOUT;
  __shared__ ushort sW[WELEM];
  const int tid  = threadIdx.x;
  const int wave = tid >> 6, lane = tid & 63;
  const int fr = lane & 15;
  const int kg = lane >> 4;
  const int r0 = bid * 128 + wave * 32;

#define STAGE_W(WT)                                                                       \
  for (int i = tid; i < WELEM / 8; i += 256){                                             \
    uint4 w = *reinterpret_cast<const uint4*>((WT) + i * 8);                              \
    uint b = (uint)i * 16u;                                                               \
    uint sb = b ^ (((b >> 8) & 7u) << 4);                                                 \
    *reinterpret_cast<uint4*>((char*)sW + sb) = w;                                        \
  }

  STAGE_W(Wt)

  const int ar0 = min(r0 + fr,      n - 1);
  const int ar1 = min(r0 + 16 + fr, n - 1);

  s16x8 ah[2][KF], al[2][KF];
  #pragma unroll
  for (int kf = 0; kf < KF; kf++){
    const float* p0 = A + (size_t)ar0 * KIN + kf * 32 + kg * 8;
    const float* p1 = A + (size_t)ar1 * KIN + kf * 32 + kg * 8;
    float4 a0 = *reinterpret_cast<const float4*>(p0);
    float4 b0 = *reinterpret_cast<const float4*>(p0 + 4);
    float4 a1 = *reinterpret_cast<const float4*>(p1);
    float4 b1 = *reinterpret_cast<const float4*>(p1 + 4);
    float f0[8] = {a0.x, a0.y, a0.z, a0.w, b0.x, b0.y, b0.z, b0.w};
    float f1[8] = {a1.x, a1.y, a1.z, a1.w, b1.x, b1.y, b1.z, b1.w};
    #pragma unroll
    for (int j = 0; j < 8; j++){
      ushort h0 = bf16_rne(f0[j]);
      ah[0][kf][j] = (short)h0;
      al[0][kf][j] = (short)bf16_rne(f0[j] - bf16f(h0));
      ushort h1 = bf16_rne(f1[j]);
      ah[1][kf][j] = (short)h1;
      al[1][kf][j] = (short)bf16_rne(f1[j] - bf16f(h1));
    }
  }
  __syncthreads();

  f32x4 acc[2][NF];

#define GEMM_PHASE()                                                                      \
  {                                                                                       \
    _Pragma("unroll")                                                                     \
    for (int nf = 0; nf < NF; nf++){                                                      \
      s16x8 wh[KF];                                                                       \
      _Pragma("unroll")                                                                   \
      for (int kf = 0; kf < KF; kf++){                                                    \
        uint b = (uint)(((nf * 16 + fr) * KIN + kf * 32 + kg * 8) * 2);                   \
        wh[kf] = *reinterpret_cast<const s16x8*>((const char*)sW + (b ^ (((b >> 8) & 7u) << 4))); \
      }                                                                                   \
      _Pragma("unroll")                                                                   \
      for (int kf = 0; kf < KF; kf++){                                                    \
        acc[0][nf] = __builtin_amdgcn_mfma_f32_16x16x32_bf16(ah[0][kf], wh[kf], acc[0][nf], 0, 0, 0); \
        acc[1][nf] = __builtin_amdgcn_mfma_f32_16x16x32_bf16(ah[1][kf], wh[kf], acc[1][nf], 0, 0, 0); \
        acc[0][nf] = __builtin_amdgcn_mfma_f32_16x16x32_bf16(al[0][kf], wh[kf], acc[0][nf], 0, 0, 0); \
        acc[1][nf] = __builtin_amdgcn_mfma_f32_16x16x32_bf16(al[1][kf], wh[kf], acc[1][nf], 0, 0, 0); \
      }                                                                                   \
    }                                                                                     \
  }

  #pragma unroll
  for (int nf = 0; nf < NF; nf++){ acc[0][nf] = (f32x4){0.f,0.f,0.f,0.f}; acc[1][nf] = (f32x4){0.f,0.f,0.f,0.f}; }
  GEMM_PHASE()

  float rowdot[2][4];
  if (FUSE){
    #pragma unroll
    for (int rg = 0; rg < 2; rg++)
      #pragma unroll
      for (int i = 0; i < 4; i++) rowdot[rg][i] = 0.f;
  }

  #pragma unroll
  for (int nf = 0; nf < NF; nf++){
    int c = nf * 16 + fr;
    float bb = bias[c];
    float w2 = FUSE ? bias2[c] : 0.f;
    float g_ = 0.f, b_ = 0.f, m_ = 0.f, v_ = 0.f;
    if (EPI == 1){ g_ = bn_g[c]; b_ = bn_b[c]; m_ = bn_m[c]; v_ = bn_v[c]; }
    #pragma unroll
    for (int rg = 0; rg < 2; rg++){
      #pragma unroll
      for (int i = 0; i < 4; i++){
        int gr = r0 + rg * 16 + kg * 4 + i;
        if (gr < n){
          float v = acc[rg][nf][i] + bb;
          if (EPI == 1){
            v = (v - m_) * rsqrtf(v_ + 1e-5f) * g_ + b_;
            v = lrelu(v, 0.1f);
          }
          if (EPI == 2){ v = lrelu(v, 0.1f); }
          if (FUSE){
            rowdot[rg][i] = fmaf(v, w2, rowdot[rg][i]);
          } else if (DUAL){
            __half hv = __float2half(v);
            OUTH[(size_t)gr * NOUT + c] = *reinterpret_cast<ushort*>(&hv);
          } else {
            OUTF[(size_t)gr * NOUT + c] = v;
          }
        }
      }
    }
  }

  if (FUSE){
    float bo2 = bn_g[0];
    #pragma unroll
    for (int rg = 0; rg < 2; rg++){
      #pragma unroll
      for (int i = 0; i < 4; i++){
        float rd = dpp_add16(rowdot[rg][i]);
        int gr = r0 + rg * 16 + kg * 4 + i;
        if (fr == 0 && gr < n) OUTF[gr] = rd + bo2;
      }
    }
  }

  if (DUAL){
    __syncthreads();           // all phase-0 reads of sW done
    STAGE_W(Wt2)
    __syncthreads();
    #pragma unroll
    for (int nf = 0; nf < NF; nf++){ acc[0][nf] = (f32x4){0.f,0.f,0.f,0.f}; acc[1][nf] = (f32x4){0.f,0.f,0.f,0.f}; }
    GEMM_PHASE()
    #pragma unroll
    for (int nf = 0; nf < NF; nf++){
      int c = nf * 16 + fr;
      float bb = bias2[c];
      #pragma unroll
      for (int rg = 0; rg < 2; rg++){
        #pragma unroll
        for (int i = 0; i < 4; i++){
          int gr = r0 + rg * 16 + kg * 4 + i;
          if (gr < n) OUTF[(size_t)gr * NOUT + c] = acc[rg][nf][i] + bb;
        }
      }
    }
  }
#undef GEMM_PHASE
#undef STAGE_W
}

// ---------------- fused GEMM + optional CSR-tail kernel ----------------
template<int KIN, int NOUT, int EPI, bool DUAL, bool FUSE, int TAIL>
__launch_bounds__(256, 4)
__global__ void mfma_gemm_kernel(const float* __restrict__ A,
                                 const ushort* __restrict__ Wt, const float* __restrict__ bias,
                                 const ushort* __restrict__ Wt2, const float* __restrict__ bias2,
                                 const float* __restrict__ bn_g, const float* __restrict__ bn_b,
                                 const float* __restrict__ bn_m, const float* __restrict__ bn_v,
                                 ushort* __restrict__ OUTH, float* __restrict__ OUTF, int n,
                                 int gemmBlocks,
                                 const int* __restrict__ ei, const int* __restrict__ flag,
                                 int* __restrict__ deg, const int* __restrict__ rowptr,
                                 int* __restrict__ csr){
  if ((int)blockIdx.x < gemmBlocks){
    gemm_body<KIN, NOUT, EPI, DUAL, FUSE>(blockIdx.x, A, Wt, bias, Wt2, bias2,
                                          bn_g, bn_b, bn_m, bn_v, OUTH, OUTF, n);
    return;
  }
  if (TAIL == 0) return;
  int e = ((int)blockIdx.x - gemmBlocks) * 256 + (int)threadIdx.x;
  if (TAIL == 1) count_body(e, ei, flag, deg);
  if (TAIL == 2) scatter_body(e, ei, flag, rowptr, deg, csr);
}

// ---------------- GATv2 edge phase (4 nodes per wave, no-max softmax) ----------------
__global__ void gat_edge_kernel(const uint* __restrict__ XLh, const float* __restrict__ XR,
                                const float* __restrict__ att, const float* __restrict__ bias,
                                const float* __restrict__ bn_g, const float* __restrict__ bn_b,
                                const float* __restrict__ bn_m, const float* __restrict__ bn_v,
                                const float* __restrict__ H, float* __restrict__ OUT,
                                const int* __restrict__ rowptr, const int* __restrict__ csr_src,
                                int n){
  const int wid  = (int)((blockIdx.x * blockDim.x + threadIdx.x) >> 6);
  const int lane = threadIdx.x & 63;
  const int nb = wid * 4;
  if (nb >= n) return;
  const int g  = lane >> 4;
  const int c4 = lane & 15;
  const int cb = c4 * 8;
  const int d  = min(nb + g, n - 1);
  const float L2E = 1.44269504f;

  float4 xr0 = *reinterpret_cast<const float4*>(XR + (size_t)d * 128 + cb);
  float4 xr1 = *reinterpret_cast<const float4*>(XR + (size_t)d * 128 + cb + 4);
  float4 at0 = *reinterpret_cast<const float4*>(att + cb);
  float4 at1 = *reinterpret_cast<const float4*>(att + cb + 4);
  __half2 xrh[4] = { __floats2half2_rn(xr0.x, xr0.y), __floats2half2_rn(xr0.z, xr0.w),
                     __floats2half2_rn(xr1.x, xr1.y), __floats2half2_rn(xr1.z, xr1.w) };
  __half2 ath[4] = { __floats2half2_rn(at0.x * L2E, at0.y * L2E), __floats2half2_rn(at0.z * L2E, at0.w * L2E),
                     __floats2half2_rn(at1.x * L2E, at1.y * L2E), __floats2half2_rn(at1.z * L2E, at1.w * L2E) };
  const __half2 c06 = __float2half2_rn(0.6f);
  const __half2 c04 = __float2half2_rn(0.4f);

  float den = 0.f;
  float O[8] = {0.f,0.f,0.f,0.f,0.f,0.f,0.f,0.f};

  const int start = rowptr[d];
  const int cnt = rowptr[d + 1] - start + 1;
  const int* __restrict__ base = csr_src + start - 1;

  int mx = cnt;
  mx = max(mx, __shfl_xor(mx, 16));
  mx = max(mx, __shfl_xor(mx, 32));

  auto IDX = [&](int s) -> int {
    int c = min(s, cnt - 1);
    return (c == 0) ? d : base[c];
  };
  auto ROW = [&](int si) -> uint4 {
    return *reinterpret_cast<const uint4*>(XLh + (size_t)si * 64 + c4 * 4);
  };

  auto PROC = [&](uint4 cur, int s){
    const bool valid = s < cnt;
    __half2 x0 = *reinterpret_cast<__half2*>(&cur.x);
    __half2 x1 = *reinterpret_cast<__half2*>(&cur.y);
    __half2 x2 = *reinterpret_cast<__half2*>(&cur.z);
    __half2 x3 = *reinterpret_cast<__half2*>(&cur.w);
    __half2 s0 = __hadd2(xrh[0], x0);
    __half2 s1 = __hadd2(xrh[1], x1);
    __half2 s2 = __hadd2(xrh[2], x2);
    __half2 s3 = __hadd2(xrh[3], x3);
    uint a0u = *reinterpret_cast<uint*>(&s0) & 0x7FFF7FFFu;
    uint a1u = *reinterpret_cast<uint*>(&s1) & 0x7FFF7FFFu;
    uint a2u = *reinterpret_cast<uint*>(&s2) & 0x7FFF7FFFu;
    uint a3u = *reinterpret_cast<uint*>(&s3) & 0x7FFF7FFFu;
    __half2 l0 = __hfma2(c06, s0, __hmul2(c04, *reinterpret_cast<__half2*>(&a0u)));
    __half2 l1 = __hfma2(c06, s1, __hmul2(c04, *reinterpret_cast<__half2*>(&a1u)));
    __half2 l2 = __hfma2(c06, s2, __hmul2(c04, *reinterpret_cast<__half2*>(&a2u)));
    __half2 l3 = __hfma2(c06, s3, __hmul2(c04, *reinterpret_cast<__half2*>(&a3u)));
#if __has_builtin(__builtin_amdgcn_fdot2)
    float acc = __builtin_amdgcn_fdot2(*reinterpret_cast<h16x2*>(&ath[0]), *reinterpret_cast<h16x2*>(&l0), 0.f, false);
    acc = __builtin_amdgcn_fdot2(*reinterpret_cast<h16x2*>(&ath[1]), *reinterpret_cast<h16x2*>(&l1), acc, false);
    acc = __builtin_amdgcn_fdot2(*reinterpret_cast<h16x2*>(&ath[2]), *reinterpret_cast<h16x2*>(&l2), acc, false);
    acc = __builtin_amdgcn_fdot2(*reinterpret_cast<h16x2*>(&ath[3]), *reinterpret_cast<h16x2*>(&l3), acc, false);
#else
    float2 q0 = __half22float2(l0), q1 = __half22float2(l1), q2 = __half22float2(l2), q3 = __half22float2(l3);
    float2 p0 = __half22float2(ath[0]), p1 = __half22float2(ath[1]), p2 = __half22float2(ath[2]), p3 = __half22float2(ath[3]);
    float acc = q0.x*p0.x + q0.y*p0.y + q1.x*p1.x + q1.y*p1.y
              + q2.x*p2.x + q2.y*p2.y + q3.x*p3.x + q3.y*p3.y;
#endif
    acc = dpp_add4(acc);
    float w = valid ? exp2f(acc) : 0.f;
    den += w;
    float2 f0 = __half22float2(x0), f1 = __half22float2(x1);
    float2 f2 = __half22float2(x2), f3 = __half22float2(x3);
    O[0] = fmaf(w, f0.x, O[0]);  O[1] = fmaf(w, f0.y, O[1]);
    O[2] = fmaf(w, f1.x, O[2]);  O[3] = fmaf(w, f1.y, O[3]);
    O[4] = fmaf(w, f2.x, O[4]);  O[5] = fmaf(w, f2.y, O[5]);
    O[6] = fmaf(w, f3.x, O[6]);  O[7] = fmaf(w, f3.y, O[7]);
  };

  uint4 r0 = ROW(IDX(0)), r1 = ROW(IDX(1)), r2 = ROW(IDX(2));
  for (int s = 0; s < mx; s++){
    int j3 = IDX(s + 3);
    PROC(r0, s);
    r0 = r1; r1 = r2; r2 = ROW(j3);
  }

  {
    float inv = 1.f / (den + 1e-16f);
    float4 bi0 = *reinterpret_cast<const float4*>(bias + cb);
    float4 bi1 = *reinterpret_cast<const float4*>(bias + cb + 4);
    float4 g0 = *reinterpret_cast<const float4*>(bn_g + cb);
    float4 g1 = *reinterpret_cast<const float4*>(bn_g + cb + 4);
    float4 bb0 = *reinterpret_cast<const float4*>(bn_b + cb);
    float4 bb1 = *reinterpret_cast<const float4*>(bn_b + cb + 4);
    float4 mm0 = *reinterpret_cast<const float4*>(bn_m + cb);
    float4 mm1 = *reinterpret_cast<const float4*>(bn_m + cb + 4);
    float4 vv0 = *reinterpret_cast<const float4*>(bn_v + cb);
    float4 vv1 = *reinterpret_cast<const float4*>(bn_v + cb + 4);
    float4 h0 = *reinterpret_cast<const float4*>(H + (size_t)d * 128 + cb);
    float4 h1 = *reinterpret_cast<const float4*>(H + (size_t)d * 128 + cb + 4);
    float bi[8] = {bi0.x,bi0.y,bi0.z,bi0.w,bi1.x,bi1.y,bi1.z,bi1.w};
    float gg[8] = {g0.x,g0.y,g0.z,g0.w,g1.x,g1.y,g1.z,g1.w};
    float bbv[8]= {bb0.x,bb0.y,bb0.z,bb0.w,bb1.x,bb1.y,bb1.z,bb1.w};
    float mmv[8]= {mm0.x,mm0.y,mm0.z,mm0.w,mm1.x,mm1.y,mm1.z,mm1.w};
    float vvv[8]= {vv0.x,vv0.y,vv0.z,vv0.w,vv1.x,vv1.y,vv1.z,vv1.w};
    float hh[8] = {h0.x,h0.y,h0.z,h0.w,h1.x,h1.y,h1.z,h1.w};
    float r[8];
    #pragma unroll
    for (int j = 0; j < 8; j++){
      float v = O[j] * inv + bi[j];
      v = (v - mmv[j]) * rsqrtf(vvv[j] + 1e-5f) * gg[j] + bbv[j];
      r[j] = lrelu(v, 0.1f) + hh[j];
    }
    *reinterpret_cast<float4*>(OUT + (size_t)d * 128 + cb)     = make_float4(r[0], r[1], r[2], r[3]);
    *reinterpret_cast<float4*>(OUT + (size_t)d * 128 + cb + 4) = make_float4(r[4], r[5], r[6], r[7]);
  }
}

// ---------------- launch ----------------
extern "C" void kernel_launch(void* const* d_in, const int* in_sizes, int n_in,
                              void* d_out, int out_size, void* d_ws, size_t ws_size,
                              hipStream_t stream) {
  const float* x     = (const float*)d_in[0];
  const int*   ei    = (const int*)  d_in[1];
  const float* W_pre = (const float*)d_in[2];
  const float* b_pre = (const float*)d_in[3];
  const float* g_pre = (const float*)d_in[4];
  const float* be_pre= (const float*)d_in[5];
  const float* m_pre = (const float*)d_in[6];
  const float* v_pre = (const float*)d_in[7];
  const float* Wl1  = (const float*)d_in[8];
  const float* bl1  = (const float*)d_in[9];
  const float* Wr1  = (const float*)d_in[10];
  const float* br1  = (const float*)d_in[11];
  const float* att1 = (const float*)d_in[12];
  const float* bias1= (const float*)d_in[13];
  const float* g1   = (const float*)d_in[14];
  const float* be1  = (const float*)d_in[15];
  const float* m1   = (const float*)d_in[16];
  const float* v1   = (const float*)d_in[17];
  const float* Wl2  = (const float*)d_in[18];
  const float* bl2  = (const float*)d_in[19];
  const float* Wr2  = (const float*)d_in[20];
  const float* br2  = (const float*)d_in[21];
  const float* att2 = (const float*)d_in[22];
  const float* bias2= (const float*)d_in[23];
  const float* g2   = (const float*)d_in[24];
  const float* be2  = (const float*)d_in[25];
  const float* m2   = (const float*)d_in[26];
  const float* v2   = (const float*)d_in[27];
  const float* Wo1  = (const float*)d_in[28];
  const float* bo1  = (const float*)d_in[29];
  const float* Wo2  = (const float*)d_in[30];
  const float* bo2  = (const float*)d_in[31];
  float* out = (float*)d_out;
  char*  ws  = (char*)d_ws;

  float*  buf0 = (float*)(ws + 0);           // [N,128] f32
  float*  buf2 = (float*)(ws + 25600000);    // [N,128] f32
  uint*   hbuf = (uint*) (ws + 51200000);    // [N,64] packed fp16 pairs
  int* rowptr = (int*)(ws + 64000000);       // N+1
  int* deg    = (int*)(ws + 64200448);       // N (reused as scatter cursor)
  int* bsum   = (int*)(ws + 64400448);       // SCAN_B
  int* boff   = (int*)(ws + 64401472);       // SCAN_B
  int* csr    = (int*)(ws + 64600448);       // E
  int* flag   = (int*)(ws + 67800448);       // 1
  ushort* wt  = (ushort*)(ws + 68000000);    // 160 KB bf16 transposed weights

  const ushort* wtPre = wt;
  const ushort* wtL1  = wt + 8192;
  const ushort* wtR1  = wt + 24576;
  const ushort* wtL2  = wt + 40960;
  const ushort* wtR2  = wt + 57344;
  const ushort* wtO1  = wt + 73728;

  const int GB = (NN + 127) / 128;   // 391 GEMM blocks
  const int GW = (NN + 15) / 16;     // edge blocks

  // A: prep_w + zero(deg) + detect
  prep_misc_kernel<<<320 + SCAN_B + 1, 256, 0, stream>>>(
      W_pre, Wl1, Wr1, Wl2, Wr2, Wo1, wt, ei, flag, deg);

  // B: pre-GEMM (buf0)  ||  count(deg)
  mfma_gemm_kernel<64, 128, 1, false, false, 1><<<GB + EB, 256, 0, stream>>>(
      x, wtPre, b_pre, nullptr, nullptr,
      g_pre, be_pre, m_pre, v_pre, nullptr, buf0, NN,
      GB, ei, flag, deg, nullptr, nullptr);

  scan1_kernel<<<SCAN_B, 256, 0, stream>>>(deg, rowptr, bsum);
  scan2_kernel<<<1, 256, 0, stream>>>(bsum, boff, rowptr);
  scan3_kernel<<<SCAN_B, 256, 0, stream>>>(rowptr, boff, deg);

  // F: layer-1 dual GEMM (hbuf, buf2)  ||  scatter(csr)
  mfma_gemm_kernel<128, 128, 0, true, false, 2><<<GB + EB, 256, 0, stream>>>(
      buf0, wtL1, bl1, wtR1, br1,
      nullptr, nullptr, nullptr, nullptr, (ushort*)hbuf, buf2, NN,
      GB, ei, flag, deg, rowptr, csr);

  gat_edge_kernel<<<GW, 256, 0, stream>>>(hbuf, buf2, att1, bias1, g1, be1, m1, v1,
                                          buf0 /*H*/, buf2 /*OUT in-place*/, rowptr, csr, NN);

  mfma_gemm_kernel<128, 128, 0, true, false, 0><<<GB, 256, 0, stream>>>(
      buf2, wtL2, bl2, wtR2, br2,
      nullptr, nullptr, nullptr, nullptr, (ushort*)hbuf, buf0, NN,
      GB, nullptr, nullptr, nullptr, nullptr, nullptr);

  gat_edge_kernel<<<GW, 256, 0, stream>>>(hbuf, buf0, att2, bias2, g2, be2, m2, v2,
                                          buf2 /*H*/, buf0 /*OUT in-place*/, rowptr, csr, NN);

  // fused out head
  mfma_gemm_kernel<128, 64, 2, false, true, 0><<<GB, 256, 0, stream>>>(
      buf0, wtO1, bo1, nullptr, Wo2,
      bo2, nullptr, nullptr, nullptr, nullptr, out, NN,
      GB, nullptr, nullptr, nullptr, nullptr, nullptr);
}

// Round 16
// 238.533 us; speedup vs baseline: 1.1728x; 1.1728x over previous
//
#include <hip/hip_runtime.h>
#include <hip/hip_bf16.h>
#include <hip/hip_fp16.h>

#define NN 50000
#define EE 800000
#define SCAN_B 196   // ceil(NN/256)
#define EB 3125      // ceil(EE/256)

typedef unsigned int uint;
typedef unsigned short ushort;
typedef __attribute__((ext_vector_type(8))) short s16x8;
typedef __attribute__((ext_vector_type(4))) float f32x4;
typedef __attribute__((ext_vector_type(2))) _Float16 h16x2;

__device__ __forceinline__ float lrelu(float x, float s){ return fmaxf(x, x * s); }

__device__ __forceinline__ ushort bf16_rne(float x){
  uint u = __float_as_uint(x);
  return (ushort)((u + 0x7FFFu + ((u >> 16) & 1u)) >> 16);
}
__device__ __forceinline__ float bf16f(ushort h){ return __uint_as_float(((uint)h) << 16); }

__device__ __forceinline__ float dpp_add4(float x){
  int v = __float_as_int(x), t;
  t = __builtin_amdgcn_update_dpp(0, v, 0xB1, 0xF, 0xF, true);
  v = __float_as_int(__int_as_float(v) + __int_as_float(t));
  t = __builtin_amdgcn_update_dpp(0, v, 0x4E, 0xF, 0xF, true);
  v = __float_as_int(__int_as_float(v) + __int_as_float(t));
  return __int_as_float(v);
}

__device__ __forceinline__ float dpp_add16(float x){
  int v = __float_as_int(x), t;
  t = __builtin_amdgcn_update_dpp(0, v, 0xB1, 0xF, 0xF, true);
  v = __float_as_int(__int_as_float(v) + __int_as_float(t));
  t = __builtin_amdgcn_update_dpp(0, v, 0x4E, 0xF, 0xF, true);
  v = __float_as_int(__int_as_float(v) + __int_as_float(t));
  t = __builtin_amdgcn_update_dpp(0, v, 0x141, 0xF, 0xF, true);
  v = __float_as_int(__int_as_float(v) + __int_as_float(t));
  t = __builtin_amdgcn_update_dpp(0, v, 0x140, 0xF, 0xF, true);
  v = __float_as_int(__int_as_float(v) + __int_as_float(t));
  return __int_as_float(v);
}

// ---------------- launch A: prep_w + zero(deg) + detect ----------------
__global__ void prep_misc_kernel(const float* __restrict__ w0, const float* __restrict__ w1,
                                 const float* __restrict__ w2, const float* __restrict__ w3,
                                 const float* __restrict__ w4, const float* __restrict__ w5,
                                 ushort* __restrict__ wt,
                                 const int* __restrict__ ei, int* __restrict__ flag,
                                 int* __restrict__ deg){
  const int b = blockIdx.x;
  if (b < 320){
    int gid = b * 256 + threadIdx.x;
    if (gid >= 81920) return;
    const int KK[6]    = {64, 128, 128, 128, 128, 128};
    const int CC[6]    = {128, 128, 128, 128, 128, 64};
    const int cumel[7] = {0, 8192, 24576, 40960, 57344, 73728, 81920};
    int j = 0;
    while (gid >= cumel[j + 1]) j++;
    int local = gid - cumel[j];
    int K = KK[j], C = CC[j];
    int k = local / C, c = local % C;
    const float* src = (j == 0) ? w0 : (j == 1) ? w1 : (j == 2) ? w2 : (j == 3) ? w3 : (j == 4) ? w4 : w5;
    wt[cumel[j] + c * K + k] = bf16_rne(src[local]);
  } else if (b < 320 + SCAN_B){
    int i = (b - 320) * 256 + threadIdx.x;
    if (i < NN) deg[i] = 0;
  } else {
    __shared__ int any;
    if (threadIdx.x == 0) any = 0;
    __syncthreads();
    if (ei[2 * threadIdx.x + 1] != 0) atomicOr(&any, 1);
    __syncthreads();
    if (threadIdx.x == 0) *flag = (any == 0) ? 1 : 0;
  }
}

// ---------------- scans ----------------
__global__ void scan1_kernel(const int* __restrict__ deg, int* __restrict__ rowptr,
                             int* __restrict__ bsum){
  __shared__ int tmp[256];
  int tid = threadIdx.x;
  int idx = blockIdx.x * 256 + tid;
  int v = (idx < NN) ? deg[idx] : 0;
  tmp[tid] = v;
  __syncthreads();
  for (int off = 1; off < 256; off <<= 1){
    int t = (tid >= off) ? tmp[tid - off] : 0;
    __syncthreads();
    tmp[tid] += t;
    __syncthreads();
  }
  if (idx < NN) rowptr[idx] = tmp[tid] - v;
  if (tid == 255) bsum[blockIdx.x] = tmp[255];
}

__global__ void scan2_kernel(const int* __restrict__ bsum, int* __restrict__ boff,
                             int* __restrict__ rowptr){
  __shared__ int tmp[256];
  int tid = threadIdx.x;
  int v = (tid < SCAN_B) ? bsum[tid] : 0;
  tmp[tid] = v;
  __syncthreads();
  for (int off = 1; off < 256; off <<= 1){
    int t = (tid >= off) ? tmp[tid - off] : 0;
    __syncthreads();
    tmp[tid] += t;
    __syncthreads();
  }
  if (tid < SCAN_B) boff[tid] = tmp[tid] - v;
  if (tid == 255) rowptr[NN] = tmp[255];
}

__global__ void scan3_kernel(int* __restrict__ rowptr, const int* __restrict__ boff,
                             int* __restrict__ deg){
  int i = blockIdx.x * 256 + threadIdx.x;
  if (i < NN){ rowptr[i] += boff[blockIdx.x]; deg[i] = 0; }   // deg -> cursor
}

// ---------------- tail bodies ----------------
__device__ __forceinline__ void count_body(int e, const int* __restrict__ ei,
                                           const int* __restrict__ flag, int* __restrict__ deg){
  if (e >= EE) return;
  int d;
  if (*flag){
    const long long* eil = (const long long*)ei;
    d = (int)eil[EE + e];
  } else {
    d = ei[EE + e];
  }
  atomicAdd(&deg[d], 1);
}

__device__ __forceinline__ void scatter_body(int e, const int* __restrict__ ei,
                                             const int* __restrict__ flag,
                                             const int* __restrict__ rowptr,
                                             int* __restrict__ cursor, int* __restrict__ csr){
  if (e >= EE) return;
  int s, d;
  if (*flag){
    const long long* eil = (const long long*)ei;
    s = (int)eil[e];
    d = (int)eil[EE + e];
  } else {
    s = ei[e];
    d = ei[EE + e];
  }
  int pos = atomicAdd(&cursor[d], 1);
  csr[rowptr[d] + pos] = s;
}

// ---------------- MFMA GEMM body (W staged ONE PHASE AT A TIME -> 32KB LDS) ----------------
template<int KIN, int NOUT, int EPI, bool DUAL, bool FUSE>
__device__ __forceinline__ void gemm_body(int bid,
                                 const float* __restrict__ A,
                                 const ushort* __restrict__ Wt, const float* __restrict__ bias,
                                 const ushort* __restrict__ Wt2, const float* __restrict__ bias2,
                                 const float* __restrict__ bn_g, const float* __restrict__ bn_b,
                                 const float* __restrict__ bn_m, const float* __restrict__ bn_v,
                                 ushort* __restrict__ OUTH, float* __restrict__ OUTF, int n){
  constexpr int KF = KIN / 32;
  constexpr int NF = NOUT / 16;
  constexpr int WELEM = KIN * NOUT;
  __shared__ ushort sW[WELEM];
  const int tid  = threadIdx.x;
  const int wave = tid >> 6, lane = tid & 63;
  const int fr = lane & 15;
  const int kg = lane >> 4;
  const int r0 = bid * 128 + wave * 32;

#define STAGE_W(WT)                                                                       \
  for (int i = tid; i < WELEM / 8; i += 256){                                             \
    uint4 w = *reinterpret_cast<const uint4*>((WT) + i * 8);                              \
    uint b = (uint)i * 16u;                                                               \
    uint sb = b ^ (((b >> 8) & 7u) << 4);                                                 \
    *reinterpret_cast<uint4*>((char*)sW + sb) = w;                                        \
  }

  STAGE_W(Wt)

  const int ar0 = min(r0 + fr,      n - 1);
  const int ar1 = min(r0 + 16 + fr, n - 1);

  s16x8 ah[2][KF], al[2][KF];
  #pragma unroll
  for (int kf = 0; kf < KF; kf++){
    const float* p0 = A + (size_t)ar0 * KIN + kf * 32 + kg * 8;
    const float* p1 = A + (size_t)ar1 * KIN + kf * 32 + kg * 8;
    float4 a0 = *reinterpret_cast<const float4*>(p0);
    float4 b0 = *reinterpret_cast<const float4*>(p0 + 4);
    float4 a1 = *reinterpret_cast<const float4*>(p1);
    float4 b1 = *reinterpret_cast<const float4*>(p1 + 4);
    float f0[8] = {a0.x, a0.y, a0.z, a0.w, b0.x, b0.y, b0.z, b0.w};
    float f1[8] = {a1.x, a1.y, a1.z, a1.w, b1.x, b1.y, b1.z, b1.w};
    #pragma unroll
    for (int j = 0; j < 8; j++){
      ushort h0 = bf16_rne(f0[j]);
      ah[0][kf][j] = (short)h0;
      al[0][kf][j] = (short)bf16_rne(f0[j] - bf16f(h0));
      ushort h1 = bf16_rne(f1[j]);
      ah[1][kf][j] = (short)h1;
      al[1][kf][j] = (short)bf16_rne(f1[j] - bf16f(h1));
    }
  }
  __syncthreads();

  f32x4 acc[2][NF];

#define GEMM_PHASE()                                                                      \
  {                                                                                       \
    _Pragma("unroll")                                                                     \
    for (int nf = 0; nf < NF; nf++){                                                      \
      s16x8 wh[KF];                                                                       \
      _Pragma("unroll")                                                                   \
      for (int kf = 0; kf < KF; kf++){                                                    \
        uint b = (uint)(((nf * 16 + fr) * KIN + kf * 32 + kg * 8) * 2);                   \
        wh[kf] = *reinterpret_cast<const s16x8*>((const char*)sW + (b ^ (((b >> 8) & 7u) << 4))); \
      }                                                                                   \
      _Pragma("unroll")                                                                   \
      for (int kf = 0; kf < KF; kf++){                                                    \
        acc[0][nf] = __builtin_amdgcn_mfma_f32_16x16x32_bf16(ah[0][kf], wh[kf], acc[0][nf], 0, 0, 0); \
        acc[1][nf] = __builtin_amdgcn_mfma_f32_16x16x32_bf16(ah[1][kf], wh[kf], acc[1][nf], 0, 0, 0); \
        acc[0][nf] = __builtin_amdgcn_mfma_f32_16x16x32_bf16(al[0][kf], wh[kf], acc[0][nf], 0, 0, 0); \
        acc[1][nf] = __builtin_amdgcn_mfma_f32_16x16x32_bf16(al[1][kf], wh[kf], acc[1][nf], 0, 0, 0); \
      }                                                                                   \
    }                                                                                     \
  }

  #pragma unroll
  for (int nf = 0; nf < NF; nf++){ acc[0][nf] = (f32x4){0.f,0.f,0.f,0.f}; acc[1][nf] = (f32x4){0.f,0.f,0.f,0.f}; }
  GEMM_PHASE()

  float rowdot[2][4];
  if (FUSE){
    #pragma unroll
    for (int rg = 0; rg < 2; rg++)
      #pragma unroll
      for (int i = 0; i < 4; i++) rowdot[rg][i] = 0.f;
  }

  #pragma unroll
  for (int nf = 0; nf < NF; nf++){
    int c = nf * 16 + fr;
    float bb = bias[c];
    float w2 = FUSE ? bias2[c] : 0.f;
    float g_ = 0.f, b_ = 0.f, m_ = 0.f, v_ = 0.f;
    if (EPI == 1){ g_ = bn_g[c]; b_ = bn_b[c]; m_ = bn_m[c]; v_ = bn_v[c]; }
    #pragma unroll
    for (int rg = 0; rg < 2; rg++){
      #pragma unroll
      for (int i = 0; i < 4; i++){
        int gr = r0 + rg * 16 + kg * 4 + i;
        if (gr < n){
          float v = acc[rg][nf][i] + bb;
          if (EPI == 1){
            v = (v - m_) * rsqrtf(v_ + 1e-5f) * g_ + b_;
            v = lrelu(v, 0.1f);
          }
          if (EPI == 2){ v = lrelu(v, 0.1f); }
          if (FUSE){
            rowdot[rg][i] = fmaf(v, w2, rowdot[rg][i]);
          } else if (DUAL){
            __half hv = __float2half(v);
            OUTH[(size_t)gr * NOUT + c] = *reinterpret_cast<ushort*>(&hv);
          } else {
            OUTF[(size_t)gr * NOUT + c] = v;
          }
        }
      }
    }
  }

  if (FUSE){
    float bo2 = bn_g[0];
    #pragma unroll
    for (int rg = 0; rg < 2; rg++){
      #pragma unroll
      for (int i = 0; i < 4; i++){
        float rd = dpp_add16(rowdot[rg][i]);
        int gr = r0 + rg * 16 + kg * 4 + i;
        if (fr == 0 && gr < n) OUTF[gr] = rd + bo2;
      }
    }
  }

  if (DUAL){
    __syncthreads();           // all phase-0 reads of sW done
    STAGE_W(Wt2)
    __syncthreads();
    #pragma unroll
    for (int nf = 0; nf < NF; nf++){ acc[0][nf] = (f32x4){0.f,0.f,0.f,0.f}; acc[1][nf] = (f32x4){0.f,0.f,0.f,0.f}; }
    GEMM_PHASE()
    #pragma unroll
    for (int nf = 0; nf < NF; nf++){
      int c = nf * 16 + fr;
      float bb = bias2[c];
      #pragma unroll
      for (int rg = 0; rg < 2; rg++){
        #pragma unroll
        for (int i = 0; i < 4; i++){
          int gr = r0 + rg * 16 + kg * 4 + i;
          if (gr < n) OUTF[(size_t)gr * NOUT + c] = acc[rg][nf][i] + bb;
        }
      }
    }
  }
#undef GEMM_PHASE
#undef STAGE_W
}

// ---------------- fused GEMM + optional CSR-tail kernel ----------------
template<int KIN, int NOUT, int EPI, bool DUAL, bool FUSE, int TAIL>
__launch_bounds__(256, 2)
__global__ void mfma_gemm_kernel(const float* __restrict__ A,
                                 const ushort* __restrict__ Wt, const float* __restrict__ bias,
                                 const ushort* __restrict__ Wt2, const float* __restrict__ bias2,
                                 const float* __restrict__ bn_g, const float* __restrict__ bn_b,
                                 const float* __restrict__ bn_m, const float* __restrict__ bn_v,
                                 ushort* __restrict__ OUTH, float* __restrict__ OUTF, int n,
                                 int gemmBlocks,
                                 const int* __restrict__ ei, const int* __restrict__ flag,
                                 int* __restrict__ deg, const int* __restrict__ rowptr,
                                 int* __restrict__ csr){
  if ((int)blockIdx.x < gemmBlocks){
    gemm_body<KIN, NOUT, EPI, DUAL, FUSE>(blockIdx.x, A, Wt, bias, Wt2, bias2,
                                          bn_g, bn_b, bn_m, bn_v, OUTH, OUTF, n);
    return;
  }
  if (TAIL == 0) return;
  int e = ((int)blockIdx.x - gemmBlocks) * 256 + (int)threadIdx.x;
  if (TAIL == 1) count_body(e, ei, flag, deg);
  if (TAIL == 2) scatter_body(e, ei, flag, rowptr, deg, csr);
}

// ---------------- GATv2 edge phase (4 nodes per wave, no-max softmax) ----------------
__global__ void gat_edge_kernel(const uint* __restrict__ XLh, const float* __restrict__ XR,
                                const float* __restrict__ att, const float* __restrict__ bias,
                                const float* __restrict__ bn_g, const float* __restrict__ bn_b,
                                const float* __restrict__ bn_m, const float* __restrict__ bn_v,
                                const float* __restrict__ H, float* __restrict__ OUT,
                                const int* __restrict__ rowptr, const int* __restrict__ csr_src,
                                int n){
  const int wid  = (int)((blockIdx.x * blockDim.x + threadIdx.x) >> 6);
  const int lane = threadIdx.x & 63;
  const int nb = wid * 4;
  if (nb >= n) return;
  const int g  = lane >> 4;
  const int c4 = lane & 15;
  const int cb = c4 * 8;
  const int d  = min(nb + g, n - 1);
  const float L2E = 1.44269504f;

  float4 xr0 = *reinterpret_cast<const float4*>(XR + (size_t)d * 128 + cb);
  float4 xr1 = *reinterpret_cast<const float4*>(XR + (size_t)d * 128 + cb + 4);
  float4 at0 = *reinterpret_cast<const float4*>(att + cb);
  float4 at1 = *reinterpret_cast<const float4*>(att + cb + 4);
  __half2 xrh[4] = { __floats2half2_rn(xr0.x, xr0.y), __floats2half2_rn(xr0.z, xr0.w),
                     __floats2half2_rn(xr1.x, xr1.y), __floats2half2_rn(xr1.z, xr1.w) };
  __half2 ath[4] = { __floats2half2_rn(at0.x * L2E, at0.y * L2E), __floats2half2_rn(at0.z * L2E, at0.w * L2E),
                     __floats2half2_rn(at1.x * L2E, at1.y * L2E), __floats2half2_rn(at1.z * L2E, at1.w * L2E) };
  const __half2 c06 = __float2half2_rn(0.6f);
  const __half2 c04 = __float2half2_rn(0.4f);

  float den = 0.f;
  float O[8] = {0.f,0.f,0.f,0.f,0.f,0.f,0.f,0.f};

  const int start = rowptr[d];
  const int cnt = rowptr[d + 1] - start + 1;
  const int* __restrict__ base = csr_src + start - 1;

  int mx = cnt;
  mx = max(mx, __shfl_xor(mx, 16));
  mx = max(mx, __shfl_xor(mx, 32));

  auto IDX = [&](int s) -> int {
    int c = min(s, cnt - 1);
    return (c == 0) ? d : base[c];
  };
  auto ROW = [&](int si) -> uint4 {
    return *reinterpret_cast<const uint4*>(XLh + (size_t)si * 64 + c4 * 4);
  };

  auto PROC = [&](uint4 cur, int s){
    const bool valid = s < cnt;
    __half2 x0 = *reinterpret_cast<__half2*>(&cur.x);
    __half2 x1 = *reinterpret_cast<__half2*>(&cur.y);
    __half2 x2 = *reinterpret_cast<__half2*>(&cur.z);
    __half2 x3 = *reinterpret_cast<__half2*>(&cur.w);
    __half2 s0 = __hadd2(xrh[0], x0);
    __half2 s1 = __hadd2(xrh[1], x1);
    __half2 s2 = __hadd2(xrh[2], x2);
    __half2 s3 = __hadd2(xrh[3], x3);
    uint a0u = *reinterpret_cast<uint*>(&s0) & 0x7FFF7FFFu;
    uint a1u = *reinterpret_cast<uint*>(&s1) & 0x7FFF7FFFu;
    uint a2u = *reinterpret_cast<uint*>(&s2) & 0x7FFF7FFFu;
    uint a3u = *reinterpret_cast<uint*>(&s3) & 0x7FFF7FFFu;
    __half2 l0 = __hfma2(c06, s0, __hmul2(c04, *reinterpret_cast<__half2*>(&a0u)));
    __half2 l1 = __hfma2(c06, s1, __hmul2(c04, *reinterpret_cast<__half2*>(&a1u)));
    __half2 l2 = __hfma2(c06, s2, __hmul2(c04, *reinterpret_cast<__half2*>(&a2u)));
    __half2 l3 = __hfma2(c06, s3, __hmul2(c04, *reinterpret_cast<__half2*>(&a3u)));
#if __has_builtin(__builtin_amdgcn_fdot2)
    float acc = __builtin_amdgcn_fdot2(*reinterpret_cast<h16x2*>(&ath[0]), *reinterpret_cast<h16x2*>(&l0), 0.f, false);
    acc = __builtin_amdgcn_fdot2(*reinterpret_cast<h16x2*>(&ath[1]), *reinterpret_cast<h16x2*>(&l1), acc, false);
    acc = __builtin_amdgcn_fdot2(*reinterpret_cast<h16x2*>(&ath[2]), *reinterpret_cast<h16x2*>(&l2), acc, false);
    acc = __builtin_amdgcn_fdot2(*reinterpret_cast<h16x2*>(&ath[3]), *reinterpret_cast<h16x2*>(&l3), acc, false);
#else
    float2 q0 = __half22float2(l0), q1 = __half22float2(l1), q2 = __half22float2(l2), q3 = __half22float2(l3);
    float2 p0 = __half22float2(ath[0]), p1 = __half22float2(ath[1]), p2 = __half22float2(ath[2]), p3 = __half22float2(ath[3]);
    float acc = q0.x*p0.x + q0.y*p0.y + q1.x*p1.x + q1.y*p1.y
              + q2.x*p2.x + q2.y*p2.y + q3.x*p3.x + q3.y*p3.y;
#endif
    acc = dpp_add4(acc);
    float w = valid ? exp2f(acc) : 0.f;
    den += w;
    float2 f0 = __half22float2(x0), f1 = __half22float2(x1);
    float2 f2 = __half22float2(x2), f3 = __half22float2(x3);
    O[0] = fmaf(w, f0.x, O[0]);  O[1] = fmaf(w, f0.y, O[1]);
    O[2] = fmaf(w, f1.x, O[2]);  O[3] = fmaf(w, f1.y, O[3]);
    O[4] = fmaf(w, f2.x, O[4]);  O[5] = fmaf(w, f2.y, O[5]);
    O[6] = fmaf(w, f3.x, O[6]);  O[7] = fmaf(w, f3.y, O[7]);
  };

  uint4 r0 = ROW(IDX(0)), r1 = ROW(IDX(1)), r2 = ROW(IDX(2));
  for (int s = 0; s < mx; s++){
    int j3 = IDX(s + 3);
    PROC(r0, s);
    r0 = r1; r1 = r2; r2 = ROW(j3);
  }

  {
    float inv = 1.f / (den + 1e-16f);
    float4 bi0 = *reinterpret_cast<const float4*>(bias + cb);
    float4 bi1 = *reinterpret_cast<const float4*>(bias + cb + 4);
    float4 g0 = *reinterpret_cast<const float4*>(bn_g + cb);
    float4 g1 = *reinterpret_cast<const float4*>(bn_g + cb + 4);
    float4 bb0 = *reinterpret_cast<const float4*>(bn_b + cb);
    float4 bb1 = *reinterpret_cast<const float4*>(bn_b + cb + 4);
    float4 mm0 = *reinterpret_cast<const float4*>(bn_m + cb);
    float4 mm1 = *reinterpret_cast<const float4*>(bn_m + cb + 4);
    float4 vv0 = *reinterpret_cast<const float4*>(bn_v + cb);
    float4 vv1 = *reinterpret_cast<const float4*>(bn_v + cb + 4);
    float4 h0 = *reinterpret_cast<const float4*>(H + (size_t)d * 128 + cb);
    float4 h1 = *reinterpret_cast<const float4*>(H + (size_t)d * 128 + cb + 4);
    float bi[8] = {bi0.x,bi0.y,bi0.z,bi0.w,bi1.x,bi1.y,bi1.z,bi1.w};
    float gg[8] = {g0.x,g0.y,g0.z,g0.w,g1.x,g1.y,g1.z,g1.w};
    float bbv[8]= {bb0.x,bb0.y,bb0.z,bb0.w,bb1.x,bb1.y,bb1.z,bb1.w};
    float mmv[8]= {mm0.x,mm0.y,mm0.z,mm0.w,mm1.x,mm1.y,mm1.z,mm1.w};
    float vvv[8]= {vv0.x,vv0.y,vv0.z,vv0.w,vv1.x,vv1.y,vv1.z,vv1.w};
    float hh[8] = {h0.x,h0.y,h0.z,h0.w,h1.x,h1.y,h1.z,h1.w};
    float r[8];
    #pragma unroll
    for (int j = 0; j < 8; j++){
      float v = O[j] * inv + bi[j];
      v = (v - mmv[j]) * rsqrtf(vvv[j] + 1e-5f) * gg[j] + bbv[j];
      r[j] = lrelu(v, 0.1f) + hh[j];
    }
    *reinterpret_cast<float4*>(OUT + (size_t)d * 128 + cb)     = make_float4(r[0], r[1], r[2], r[3]);
    *reinterpret_cast<float4*>(OUT + (size_t)d * 128 + cb + 4) = make_float4(r[4], r[5], r[6], r[7]);
  }
}

// ---------------- launch ----------------
extern "C" void kernel_launch(void* const* d_in, const int* in_sizes, int n_in,
                              void* d_out, int out_size, void* d_ws, size_t ws_size,
                              hipStream_t stream) {
  const float* x     = (const float*)d_in[0];
  const int*   ei    = (const int*)  d_in[1];
  const float* W_pre = (const float*)d_in[2];
  const float* b_pre = (const float*)d_in[3];
  const float* g_pre = (const float*)d_in[4];
  const float* be_pre= (const float*)d_in[5];
  const float* m_pre = (const float*)d_in[6];
  const float* v_pre = (const float*)d_in[7];
  const float* Wl1  = (const float*)d_in[8];
  const float* bl1  = (const float*)d_in[9];
  const float* Wr1  = (const float*)d_in[10];
  const float* br1  = (const float*)d_in[11];
  const float* att1 = (const float*)d_in[12];
  const float* bias1= (const float*)d_in[13];
  const float* g1   = (const float*)d_in[14];
  const float* be1  = (const float*)d_in[15];
  const float* m1   = (const float*)d_in[16];
  const float* v1   = (const float*)d_in[17];
  const float* Wl2  = (const float*)d_in[18];
  const float* bl2  = (const float*)d_in[19];
  const float* Wr2  = (const float*)d_in[20];
  const float* br2  = (const float*)d_in[21];
  const float* att2 = (const float*)d_in[22];
  const float* bias2= (const float*)d_in[23];
  const float* g2   = (const float*)d_in[24];
  const float* be2  = (const float*)d_in[25];
  const float* m2   = (const float*)d_in[26];
  const float* v2   = (const float*)d_in[27];
  const float* Wo1  = (const float*)d_in[28];
  const float* bo1  = (const float*)d_in[29];
  const float* Wo2  = (const float*)d_in[30];
  const float* bo2  = (const float*)d_in[31];
  float* out = (float*)d_out;
  char*  ws  = (char*)d_ws;

  float*  buf0 = (float*)(ws + 0);           // [N,128] f32
  float*  buf2 = (float*)(ws + 25600000);    // [N,128] f32
  uint*   hbuf = (uint*) (ws + 51200000);    // [N,64] packed fp16 pairs
  int* rowptr = (int*)(ws + 64000000);       // N+1
  int* deg    = (int*)(ws + 64200448);       // N (reused as scatter cursor)
  int* bsum   = (int*)(ws + 64400448);       // SCAN_B
  int* boff   = (int*)(ws + 64401472);       // SCAN_B
  int* csr    = (int*)(ws + 64600448);       // E
  int* flag   = (int*)(ws + 67800448);       // 1
  ushort* wt  = (ushort*)(ws + 68000000);    // 160 KB bf16 transposed weights

  const ushort* wtPre = wt;
  const ushort* wtL1  = wt + 8192;
  const ushort* wtR1  = wt + 24576;
  const ushort* wtL2  = wt + 40960;
  const ushort* wtR2  = wt + 57344;
  const ushort* wtO1  = wt + 73728;

  const int GB = (NN + 127) / 128;   // 391 GEMM blocks
  const int GW = (NN + 15) / 16;     // edge blocks

  // A: prep_w + zero(deg) + detect
  prep_misc_kernel<<<320 + SCAN_B + 1, 256, 0, stream>>>(
      W_pre, Wl1, Wr1, Wl2, Wr2, Wo1, wt, ei, flag, deg);

  // B: pre-GEMM (buf0)  ||  count(deg)
  mfma_gemm_kernel<64, 128, 1, false, false, 1><<<GB + EB, 256, 0, stream>>>(
      x, wtPre, b_pre, nullptr, nullptr,
      g_pre, be_pre, m_pre, v_pre, nullptr, buf0, NN,
      GB, ei, flag, deg, nullptr, nullptr);

  scan1_kernel<<<SCAN_B, 256, 0, stream>>>(deg, rowptr, bsum);
  scan2_kernel<<<1, 256, 0, stream>>>(bsum, boff, rowptr);
  scan3_kernel<<<SCAN_B, 256, 0, stream>>>(rowptr, boff, deg);

  // F: layer-1 dual GEMM (hbuf, buf2)  ||  scatter(csr)
  mfma_gemm_kernel<128, 128, 0, true, false, 2><<<GB + EB, 256, 0, stream>>>(
      buf0, wtL1, bl1, wtR1, br1,
      nullptr, nullptr, nullptr, nullptr, (ushort*)hbuf, buf2, NN,
      GB, ei, flag, deg, rowptr, csr);

  gat_edge_kernel<<<GW, 256, 0, stream>>>(hbuf, buf2, att1, bias1, g1, be1, m1, v1,
                                          buf0 /*H*/, buf2 /*OUT in-place*/, rowptr, csr, NN);

  mfma_gemm_kernel<128, 128, 0, true, false, 0><<<GB, 256, 0, stream>>>(
      buf2, wtL2, bl2, wtR2, br2,
      nullptr, nullptr, nullptr, nullptr, (ushort*)hbuf, buf0, NN,
      GB, nullptr, nullptr, nullptr, nullptr, nullptr);

  gat_edge_kernel<<<GW, 256, 0, stream>>>(hbuf, buf0, att2, bias2, g2, be2, m2, v2,
                                          buf2 /*H*/, buf0 /*OUT in-place*/, rowptr, csr, NN);

  // fused out head
  mfma_gemm_kernel<128, 64, 2, false, true, 0><<<GB, 256, 0, stream>>>(
      buf0, wtO1, bo1, nullptr, Wo2,
      bo2, nullptr, nullptr, nullptr, nullptr, out, NN,
      GB, nullptr, nullptr, nullptr, nullptr, nullptr);
}